// Round 3
// baseline (264.604 us; speedup 1.0000x reference)
//
#include <hip/hip_runtime.h>

// out[b,n,m] = cost_class + cost_mask + cost_dice
//   dot[b,n,m] = sum_l sigmoid(p[b,n,l]) * t[b,m,l]   (bf16 MFMA, fp32 acc)
//   sum_p[b,n] = sum_l sigmoid(p)  (fp32 path)
//   sum_t[b,m] = sum_l t           (fp32 path)
//   cost_class = -logits[b,n,label[b,m]]
//   cost_mask  = -(2*dot + L - sum_p - sum_t)/L
//   cost_dice  = 1 - (2*dot + 1)/(sum_p + sum_t + 1)
//
// Split-K blocks accumulate into a 38 KB global region via device-scope
// atomicAdd (zeroed first - d_ws is poisoned 0xAA every call), so the
// finalize kernel is 3 loads/thread instead of a 128-iteration ws loop.

#define Lsz 65536
#define Bb 4
#define Nn 100
#define Mm 20
#define Cc 81
#define CS 128                   // l-chunk per staging pass
#define NP 112                   // padded N stride in accum dot region
#define APp (20 * NP + NP + 32)  // 2240 dot + 112 sum_p + 32 sum_t = 2384 floats
#define KSTR 136                 // LDS row stride in ushorts (128 bf16 + 8 pad)
#define KBW 256                  // split-K blocks per batch (1024 total, 4/CU)

typedef short bf16x8 __attribute__((ext_vector_type(8)));
typedef float fx4 __attribute__((ext_vector_type(4)));

__device__ __forceinline__ float sigmoid_fast(float x) {
    float e = __builtin_amdgcn_exp2f(x * -1.44269504088896340736f);
    return __builtin_amdgcn_rcpf(1.0f + e);
}

__device__ __forceinline__ ushort bf16rne(float f) {
    union { float f; unsigned u; } v; v.f = f;
    unsigned u = v.u;
    u += 0x7fffu + ((u >> 16) & 1u);
    return (ushort)(u >> 16);
}

__global__ __launch_bounds__(256) void hung_zero(float* __restrict__ ac) {
    int t = blockIdx.x * 256 + threadIdx.x;
    if (t < Bb * APp) ac[t] = 0.f;
}

__global__ __launch_bounds__(256) void hung_main(
    const float* __restrict__ pm,   // (B,N,L)
    const float* __restrict__ gm,   // (B,M,L)
    float* __restrict__ ac)         // (B, APp) atomic accumulators
{
    __shared__ __align__(16) ushort ldsA[NP * KSTR];  // sigma(p) bf16, [n][k]
    __shared__ __align__(16) ushort ldsB[32 * KSTR];  // t bf16, [m][k]

    const int tid  = threadIdx.x;
    const int slot = blockIdx.x;
    const int b    = blockIdx.y;
    const int q    = tid & 31;        // float4-quad within 128-float row chunk
    const int rr   = tid >> 5;        // 0..7, row phase
    const int lane = tid & 63;
    const int w    = tid >> 6;        // wave 0..3
    const int lr   = lane & 15;
    const int kg   = lane >> 4;       // 0..3

    const int NCH = (Lsz / CS) / KBW; // chunks per block (=2)

    float sp[13], st[3];
    #pragma unroll
    for (int p = 0; p < 13; ++p) sp[p] = 0.f;
    #pragma unroll
    for (int p = 0; p < 3; ++p) st[p] = 0.f;

    fx4 acc00 = {0.f, 0.f, 0.f, 0.f};
    fx4 acc01 = {0.f, 0.f, 0.f, 0.f};
    fx4 acc10 = {0.f, 0.f, 0.f, 0.f};
    fx4 acc11 = {0.f, 0.f, 0.f, 0.f};

    const float* pbase = pm + (size_t)b * Nn * Lsz + 4 * q;
    const float* tbase = gm + (size_t)b * Mm * Lsz + 4 * q;

    for (int c = 0; c < NCH; ++c) {
        const int l0 = (slot * NCH + c) * CS;
        __syncthreads();  // prev chunk's LDS reads done before overwrite

        // ---- stage A: sigma(pred_masks) -> bf16 LDS [n][k]
        #pragma unroll
        for (int p = 0; p < 13; ++p) {
            const int r = rr + 8 * p;
            if (r < Nn) {
                float4 v = *(const float4*)(pbase + (size_t)r * Lsz + l0);
                float s0 = sigmoid_fast(v.x), s1 = sigmoid_fast(v.y);
                float s2 = sigmoid_fast(v.z), s3 = sigmoid_fast(v.w);
                sp[p] += (s0 + s1) + (s2 + s3);
                ushort4 o = { bf16rne(s0), bf16rne(s1), bf16rne(s2), bf16rne(s3) };
                *(ushort4*)&ldsA[r * KSTR + 4 * q] = o;
            }
        }
        // ---- stage B: gt_masks -> bf16 LDS [m][k]
        #pragma unroll
        for (int p = 0; p < 3; ++p) {
            const int r = rr + 8 * p;
            if (r < Mm) {
                float4 v = *(const float4*)(tbase + (size_t)r * Lsz + l0);
                st[p] += (v.x + v.y) + (v.z + v.w);
                ushort4 o = { bf16rne(v.x), bf16rne(v.y), bf16rne(v.z), bf16rne(v.w) };
                *(ushort4*)&ldsB[r * KSTR + 4 * q] = o;
            }
        }
        __syncthreads();

        // ---- MFMA: wave w owns n-tiles {2w, 2w+1}, m-tiles {0,1}
        #pragma unroll
        for (int kk = 0; kk < 4; ++kk) {
            const int ko = kk * 32 + kg * 8;  // ushort offset within row
            bf16x8 a0 = *(const bf16x8*)&ldsA[(32 * w + lr) * KSTR + ko];
            bf16x8 b0 = *(const bf16x8*)&ldsB[lr * KSTR + ko];
            bf16x8 b1 = *(const bf16x8*)&ldsB[(16 + lr) * KSTR + ko];
            acc00 = __builtin_amdgcn_mfma_f32_16x16x32_bf16(a0, b0, acc00, 0, 0, 0);
            acc01 = __builtin_amdgcn_mfma_f32_16x16x32_bf16(a0, b1, acc01, 0, 0, 0);
            if (w < 3) {  // n-tile rows 112..127 don't exist
                bf16x8 a1 = *(const bf16x8*)&ldsA[(32 * w + 16 + lr) * KSTR + ko];
                acc10 = __builtin_amdgcn_mfma_f32_16x16x32_bf16(a1, b0, acc10, 0, 0, 0);
                acc11 = __builtin_amdgcn_mfma_f32_16x16x32_bf16(a1, b1, acc11, 0, 0, 0);
            }
        }
    }

    // ---- reduce sum_p / sum_t across the 32 q-lanes of each row group
    #pragma unroll
    for (int p = 0; p < 13; ++p)
        #pragma unroll
        for (int o = 16; o > 0; o >>= 1) sp[p] += __shfl_xor(sp[p], o, 32);
    #pragma unroll
    for (int p = 0; p < 3; ++p)
        #pragma unroll
        for (int o = 16; o > 0; o >>= 1) st[p] += __shfl_xor(st[p], o, 32);

    float* acb = ac + (size_t)b * APp;
    if ((tid & 31) == 0) {
        #pragma unroll
        for (int p = 0; p < 13; ++p) {
            const int r = rr + 8 * p;
            if (r < Nn) atomicAdd(&acb[20 * NP + r], sp[p]);
        }
        #pragma unroll
        for (int p = 0; p < 3; ++p) {
            const int r = rr + 8 * p;
            if (r < Mm) atomicAdd(&acb[20 * NP + NP + r], st[p]);
        }
    }

    // ---- dot partials: D col = lane&15 (m), row = kg*4 + reg (n-local)
    const int nb = 32 * w + kg * 4;
    #pragma unroll
    for (int e = 0; e < 4; ++e) {
        const int n0 = nb + e;
        if (n0 < Nn) {
            atomicAdd(&acb[lr * NP + n0], acc00[e]);
            if (lr < 4) atomicAdd(&acb[(16 + lr) * NP + n0], acc01[e]);
        }
        const int n1 = nb + 16 + e;
        if (w < 3 && n1 < Nn) {
            atomicAdd(&acb[lr * NP + n1], acc10[e]);
            if (lr < 4) atomicAdd(&acb[(16 + lr) * NP + n1], acc11[e]);
        }
    }
}

__global__ __launch_bounds__(256) void hung_fin(
    const float* __restrict__ ac,
    const float* __restrict__ logits,   // (B,N,C)
    const int*   __restrict__ labels,   // (B,M)
    float* __restrict__ out)            // (B,N,M)
{
    int t = blockIdx.x * 256 + threadIdx.x;
    if (t >= Bb * Nn * Mm) return;
    int b = t / (Nn * Mm);
    int r = t % (Nn * Mm);
    int m = r / Nn;       // n fast-varying -> coalesced accum reads
    int n = r % Nn;

    const float* acb = ac + (size_t)b * APp;
    float dot = acb[m * NP + n];
    float sp  = acb[20 * NP + n];
    float st  = acb[20 * NP + NP + m];

    int lab = labels[b * Mm + m];
    float cc = -logits[(size_t)(b * Nn + n) * Cc + lab];
    const float invL = 1.0f / (float)Lsz;
    float cm = -(2.f * dot + (float)Lsz - sp - st) * invL;
    float cd = 1.f - (2.f * dot + 1.f) / (sp + st + 1.f);
    out[(size_t)b * (Nn * Mm) + n * Mm + m] = cc + cm + cd;
}

extern "C" void kernel_launch(void* const* d_in, const int* in_sizes, int n_in,
                              void* d_out, int out_size, void* d_ws, size_t ws_size,
                              hipStream_t stream) {
    const float* logits = (const float*)d_in[0];
    const float* pmasks = (const float*)d_in[1];
    const int*   labels = (const int*)d_in[2];
    const float* gmasks = (const float*)d_in[3];
    float* out = (float*)d_out;
    float* ac  = (float*)d_ws;  // Bb*APp floats = 38 KB

    hung_zero<<<(Bb * APp + 255) / 256, 256, 0, stream>>>(ac);
    hung_main<<<dim3(KBW, Bb), 256, 0, stream>>>(pmasks, gmasks, ac);
    hung_fin<<<(Bb * Nn * Mm + 255) / 256, 256, 0, stream>>>(ac, logits, labels, out);
}

// Round 4
// 224.541 us; speedup vs baseline: 1.1784x; 1.1784x over previous
//
#include <hip/hip_runtime.h>

// out[b,n,m] = cost_class + cost_mask + cost_dice
//   dot[b,n,m] = sum_l sigmoid(p[b,n,l]) * t[b,m,l]   (bf16 MFMA, fp32 acc)
//   sum_p[b,n] = sum_l sigmoid(p); sum_t[b,m] = sum_l t   (fp32 paths)
//   cost_class = -logits[b,n,label[b,m]]
//   cost_mask  = -(2*dot + L - sum_p - sum_t)/L
//   cost_dice  = 1 - (2*dot + 1)/(sum_p + sum_t + 1)
//
// LDS-free design: each lane loads its MFMA fragment's 8 consecutive fp32
// directly from global (A-frag layout: lane kg*16+lr = row lr, k kg*8..+8,
// HW-verified in rounds 2/3), applies sigmoid / bf16-pack in registers, and
// feeds MFMA. No barriers -> k-loop pipelines freely; no atomics (round-3
// post-mortem: 2.17M contended atomicAdds cost ~80us); plain coalesced
// split-K partial stores + tiny reduce kernel.

#define Lsz 65536
#define Bb 4
#define Nn 100
#define Mm 20
#define Cc 81
#define NP 112                  // padded N stride in ws dot region
#define SP_OFF (20 * NP)        // 2240: sum_p region
#define ST_OFF (20 * NP + NP)   // 2352: sum_t region
#define Pp (20 * NP + NP + 32)  // 2384 floats per (b,slot)
#define KBW 256                 // split-K slots per batch -> 1024 blocks
#define RL (Lsz / KBW)          // 256 l-values per block

typedef short bf16x8 __attribute__((ext_vector_type(8)));
typedef float fx4 __attribute__((ext_vector_type(4)));

__device__ __forceinline__ float sigmoid_fast(float x) {
    float e = __builtin_amdgcn_exp2f(x * -1.44269504088896340736f);
    return __builtin_amdgcn_rcpf(1.0f + e);
}

__device__ __forceinline__ ushort bf16rne(float f) {
    union { float f; unsigned u; } v; v.f = f;
    unsigned u = v.u;
    u += 0x7fffu + ((u >> 16) & 1u);
    return (ushort)(u >> 16);
}

__device__ __forceinline__ bf16x8 pack8(float a, float b, float c, float d,
                                        float e, float f, float g, float h) {
    bf16x8 r;
    r[0] = (short)bf16rne(a); r[1] = (short)bf16rne(b);
    r[2] = (short)bf16rne(c); r[3] = (short)bf16rne(d);
    r[4] = (short)bf16rne(e); r[5] = (short)bf16rne(f);
    r[6] = (short)bf16rne(g); r[7] = (short)bf16rne(h);
    return r;
}

__global__ __launch_bounds__(256) void hung_main(
    const float* __restrict__ pm,   // (B,N,L)
    const float* __restrict__ gm,   // (B,M,L)
    float* __restrict__ ws)         // (B,KBW,Pp) partials
{
    const int tid  = threadIdx.x;
    const int slot = blockIdx.x;
    const int b    = blockIdx.y;
    const int lane = tid & 63;
    const int w    = tid >> 6;     // wave 0..3: owns n-tiles {2w, 2w+1}
    const int lr   = lane & 15;
    const int kg   = lane >> 4;

    const int  rA0  = 32 * w + lr;        // n row of a0 fragment
    const int  rA1  = 32 * w + 16 + lr;   // n row of a1 fragment
    const bool vA0  = rA0 < Nn;           // false only for w==3, lr>=4
    const bool wlt3 = (w < 3);            // a1 tile exists
    const bool vB1  = (16 + lr) < Mm;     // lr < 4

    const int l0 = slot * RL + kg * 8;
    // clamp invalid rows to row 0: reads stay in-bounds, results are
    // discarded at store time (store guards are the source of truth).
    const float* pA0 = pm + ((size_t)b * Nn + (vA0 ? rA0 : 0)) * Lsz + l0;
    const float* pA1 = pm + ((size_t)b * Nn + (wlt3 ? rA1 : 0)) * Lsz + l0;
    const float* pB0 = gm + ((size_t)b * Mm + lr) * Lsz + l0;
    const float* pB1 = gm + ((size_t)b * Mm + (vB1 ? 16 + lr : 0)) * Lsz + l0;

    fx4 acc00 = {0.f, 0.f, 0.f, 0.f};
    fx4 acc01 = {0.f, 0.f, 0.f, 0.f};
    fx4 acc10 = {0.f, 0.f, 0.f, 0.f};
    fx4 acc11 = {0.f, 0.f, 0.f, 0.f};
    float spA = 0.f, spB = 0.f, st0 = 0.f, st1 = 0.f;

    #pragma unroll 2
    for (int kk = 0; kk < RL / 32; ++kk) {
        const int o = kk * 32;
        float4 a0l = *(const float4*)(pA0 + o), a0h = *(const float4*)(pA0 + o + 4);
        float4 b0l = *(const float4*)(pB0 + o), b0h = *(const float4*)(pB0 + o + 4);
        float4 b1l = *(const float4*)(pB1 + o), b1h = *(const float4*)(pB1 + o + 4);

        float s0 = sigmoid_fast(a0l.x), s1 = sigmoid_fast(a0l.y);
        float s2 = sigmoid_fast(a0l.z), s3 = sigmoid_fast(a0l.w);
        float s4 = sigmoid_fast(a0h.x), s5 = sigmoid_fast(a0h.y);
        float s6 = sigmoid_fast(a0h.z), s7 = sigmoid_fast(a0h.w);
        spA += ((s0 + s1) + (s2 + s3)) + ((s4 + s5) + (s6 + s7));
        bf16x8 fa0 = pack8(s0, s1, s2, s3, s4, s5, s6, s7);
        bf16x8 fb0 = pack8(b0l.x, b0l.y, b0l.z, b0l.w, b0h.x, b0h.y, b0h.z, b0h.w);
        bf16x8 fb1 = pack8(b1l.x, b1l.y, b1l.z, b1l.w, b1h.x, b1h.y, b1h.z, b1h.w);

        if (w == 0) {  // count each t element once per block
            st0 += ((b0l.x + b0l.y) + (b0l.z + b0l.w)) + ((b0h.x + b0h.y) + (b0h.z + b0h.w));
            st1 += ((b1l.x + b1l.y) + (b1l.z + b1l.w)) + ((b1h.x + b1h.y) + (b1h.z + b1h.w));
        }

        acc00 = __builtin_amdgcn_mfma_f32_16x16x32_bf16(fa0, fb0, acc00, 0, 0, 0);
        acc01 = __builtin_amdgcn_mfma_f32_16x16x32_bf16(fa0, fb1, acc01, 0, 0, 0);

        if (wlt3) {
            float4 a1l = *(const float4*)(pA1 + o), a1h = *(const float4*)(pA1 + o + 4);
            float t0 = sigmoid_fast(a1l.x), t1 = sigmoid_fast(a1l.y);
            float t2 = sigmoid_fast(a1l.z), t3 = sigmoid_fast(a1l.w);
            float t4 = sigmoid_fast(a1h.x), t5 = sigmoid_fast(a1h.y);
            float t6 = sigmoid_fast(a1h.z), t7 = sigmoid_fast(a1h.w);
            spB += ((t0 + t1) + (t2 + t3)) + ((t4 + t5) + (t6 + t7));
            bf16x8 fa1 = pack8(t0, t1, t2, t3, t4, t5, t6, t7);
            acc10 = __builtin_amdgcn_mfma_f32_16x16x32_bf16(fa1, fb0, acc10, 0, 0, 0);
            acc11 = __builtin_amdgcn_mfma_f32_16x16x32_bf16(fa1, fb1, acc11, 0, 0, 0);
        }
    }

    // reduce row-sums across the 4 kg lane-groups (lanes lr, 16+lr, 32+lr, 48+lr)
    spA += __shfl_xor(spA, 16, 64); spA += __shfl_xor(spA, 32, 64);
    spB += __shfl_xor(spB, 16, 64); spB += __shfl_xor(spB, 32, 64);
    st0 += __shfl_xor(st0, 16, 64); st0 += __shfl_xor(st0, 32, 64);
    st1 += __shfl_xor(st1, 16, 64); st1 += __shfl_xor(st1, 32, 64);

    float* wsb = ws + (size_t)(b * KBW + slot) * Pp;
    if (lane < 16) {  // kg==0, lr==lane
        if (vA0)  wsb[SP_OFF + rA0] = spA;
        if (wlt3) wsb[SP_OFF + rA1] = spB;
        if (w == 0) {
            wsb[ST_OFF + lr] = st0;
            if (lr < 4) wsb[ST_OFF + 16 + lr] = st1;
        }
    }

    // dot partials: C/D layout col=lane&15 (m), row=kg*4+e (n-local); each
    // acc fx4 covers 4 consecutive n -> float4 stores.
    const int nb = 32 * w + kg * 4;
    if (nb < Nn) {
        *(float4*)&wsb[lr * NP + nb] = *(float4*)&acc00;
        if (lr < 4) *(float4*)&wsb[(16 + lr) * NP + nb] = *(float4*)&acc01;
    }
    if (wlt3) {
        *(float4*)&wsb[lr * NP + nb + 16] = *(float4*)&acc10;
        if (lr < 4) *(float4*)&wsb[(16 + lr) * NP + nb + 16] = *(float4*)&acc11;
    }
}

__global__ __launch_bounds__(256) void hung_fin(
    const float* __restrict__ ws,
    const float* __restrict__ logits,   // (B,N,C)
    const int*   __restrict__ labels,   // (B,M)
    float* __restrict__ out)            // (B,N,M)
{
    int t = blockIdx.x * 256 + threadIdx.x;
    if (t >= Bb * Nn * Mm) return;
    int b = t / (Nn * Mm);
    int r = t % (Nn * Mm);
    int m = r / Nn;       // n fast-varying -> per-wave coalesced ws reads
    int n = r % Nn;

    const float* p = ws + (size_t)b * KBW * Pp;
    float dot = 0.f, sp = 0.f, st = 0.f;
    #pragma unroll 4
    for (int kb = 0; kb < KBW; ++kb) {
        dot += p[m * NP + n];
        sp  += p[SP_OFF + n];
        st  += p[ST_OFF + m];
        p += Pp;
    }

    int lab = labels[b * Mm + m];
    float cc = -logits[(size_t)(b * Nn + n) * Cc + lab];
    const float invL = 1.0f / (float)Lsz;
    float cm = -(2.f * dot + (float)Lsz - sp - st) * invL;
    float cd = 1.f - (2.f * dot + 1.f) / (sp + st + 1.f);
    out[(size_t)b * (Nn * Mm) + n * Mm + m] = cc + cm + cd;
}

extern "C" void kernel_launch(void* const* d_in, const int* in_sizes, int n_in,
                              void* d_out, int out_size, void* d_ws, size_t ws_size,
                              hipStream_t stream) {
    const float* logits = (const float*)d_in[0];
    const float* pmasks = (const float*)d_in[1];
    const int*   labels = (const int*)d_in[2];
    const float* gmasks = (const float*)d_in[3];
    float* out = (float*)d_out;
    float* ws  = (float*)d_ws;  // Bb*KBW*Pp floats = 9.8 MB

    hung_main<<<dim3(KBW, Bb), 256, 0, stream>>>(pmasks, gmasks, ws);
    hung_fin<<<(Bb * Nn * Mm + 255) / 256, 256, 0, stream>>>(ws, logits, labels, out);
}

// Round 5
// 214.869 us; speedup vs baseline: 1.2315x; 1.0450x over previous
//
#include <hip/hip_runtime.h>

// out[b,n,m] = cost_class + cost_mask + cost_dice
//   dot[b,n,m] = sum_l sigmoid(p[b,n,l]) * t[b,m,l]   (bf16 MFMA, fp32 acc)
//   sum_p[b,n] = sum_l sigmoid(p); sum_t[b,m] = sum_l t   (fp32 paths)
//   cost_class = -logits[b,n,label[b,m]]
//   cost_mask  = -(2*dot + L - sum_p - sum_t)/L
//   cost_dice  = 1 - (2*dot + 1)/(sum_p + sum_t + 1)
//
// LDS-free main: each lane loads its MFMA fragment's 8 consecutive fp32
// directly from global, sigmoids/packs in registers, feeds MFMA. No barriers,
// no atomics. KBW=512 split-K -> 2048 blocks, 8 blocks/CU (VGPR<=64, LDS=0)
// = 32 waves/CU for latency hiding. Partial reduction is hierarchical:
// hung_red (512 slots -> 16 groups, coalesced) then hung_fin (16 iters).

#define Lsz 65536
#define Bb 4
#define Nn 100
#define Mm 20
#define Cc 81
#define NP 112                  // padded N stride in ws dot region
#define SP_OFF (20 * NP)        // 2240: sum_p region
#define ST_OFF (20 * NP + NP)   // 2352: sum_t region
#define Pp (20 * NP + NP + 32)  // 2384 floats per (b,slot)
#define KBW 512                 // split-K slots per batch -> 2048 blocks
#define RL (Lsz / KBW)          // 128 l-values per block
#define GRP 16                  // reduction groups
#define SPG (KBW / GRP)         // 32 slots per group
#define JC 4                    // j-chunks in hung_red

typedef short bf16x8 __attribute__((ext_vector_type(8)));
typedef float fx4 __attribute__((ext_vector_type(4)));

__device__ __forceinline__ float sigmoid_fast(float x) {
    float e = __builtin_amdgcn_exp2f(x * -1.44269504088896340736f);
    return __builtin_amdgcn_rcpf(1.0f + e);
}

__device__ __forceinline__ ushort bf16rne(float f) {
    union { float f; unsigned u; } v; v.f = f;
    unsigned u = v.u;
    u += 0x7fffu + ((u >> 16) & 1u);
    return (ushort)(u >> 16);
}

__device__ __forceinline__ bf16x8 pack8(float a, float b, float c, float d,
                                        float e, float f, float g, float h) {
    bf16x8 r;
    r[0] = (short)bf16rne(a); r[1] = (short)bf16rne(b);
    r[2] = (short)bf16rne(c); r[3] = (short)bf16rne(d);
    r[4] = (short)bf16rne(e); r[5] = (short)bf16rne(f);
    r[6] = (short)bf16rne(g); r[7] = (short)bf16rne(h);
    return r;
}

__global__ __launch_bounds__(256, 8) void hung_main(
    const float* __restrict__ pm,   // (B,N,L)
    const float* __restrict__ gm,   // (B,M,L)
    float* __restrict__ ws)         // (B,KBW,Pp) partials
{
    const int tid  = threadIdx.x;
    const int slot = blockIdx.x;
    const int b    = blockIdx.y;
    const int lane = tid & 63;
    const int w    = tid >> 6;     // wave 0..3: owns n-tiles {2w, 2w+1}
    const int lr   = lane & 15;
    const int kg   = lane >> 4;

    const int  rA0  = 32 * w + lr;        // n row of a0 fragment
    const int  rA1  = 32 * w + 16 + lr;   // n row of a1 fragment
    const bool vA0  = rA0 < Nn;           // false only for w==3, lr>=4
    const bool wlt3 = (w < 3);            // a1 tile exists
    const bool vB1  = (16 + lr) < Mm;     // lr < 4

    const int l0 = slot * RL + kg * 8;
    // clamp invalid rows to row 0: reads stay in-bounds (L1 hits), results
    // discarded at store time (store guards are the source of truth).
    const float* pA0 = pm + ((size_t)b * Nn + (vA0 ? rA0 : 0)) * Lsz + l0;
    const float* pA1 = pm + ((size_t)b * Nn + (wlt3 ? rA1 : 0)) * Lsz + l0;
    const float* pB0 = gm + ((size_t)b * Mm + lr) * Lsz + l0;
    const float* pB1 = gm + ((size_t)b * Mm + (vB1 ? 16 + lr : 0)) * Lsz + l0;

    fx4 acc00 = {0.f, 0.f, 0.f, 0.f};
    fx4 acc01 = {0.f, 0.f, 0.f, 0.f};
    fx4 acc10 = {0.f, 0.f, 0.f, 0.f};
    fx4 acc11 = {0.f, 0.f, 0.f, 0.f};
    float spA = 0.f, spB = 0.f, st0 = 0.f, st1 = 0.f;

    #pragma unroll 2
    for (int kk = 0; kk < RL / 32; ++kk) {
        const int o = kk * 32;
        float4 a0l = *(const float4*)(pA0 + o), a0h = *(const float4*)(pA0 + o + 4);
        float4 b0l = *(const float4*)(pB0 + o), b0h = *(const float4*)(pB0 + o + 4);
        float4 b1l = *(const float4*)(pB1 + o), b1h = *(const float4*)(pB1 + o + 4);

        float s0 = sigmoid_fast(a0l.x), s1 = sigmoid_fast(a0l.y);
        float s2 = sigmoid_fast(a0l.z), s3 = sigmoid_fast(a0l.w);
        float s4 = sigmoid_fast(a0h.x), s5 = sigmoid_fast(a0h.y);
        float s6 = sigmoid_fast(a0h.z), s7 = sigmoid_fast(a0h.w);
        spA += ((s0 + s1) + (s2 + s3)) + ((s4 + s5) + (s6 + s7));
        bf16x8 fa0 = pack8(s0, s1, s2, s3, s4, s5, s6, s7);
        bf16x8 fb0 = pack8(b0l.x, b0l.y, b0l.z, b0l.w, b0h.x, b0h.y, b0h.z, b0h.w);
        bf16x8 fb1 = pack8(b1l.x, b1l.y, b1l.z, b1l.w, b1h.x, b1h.y, b1h.z, b1h.w);

        if (w == 0) {  // count each t element once per block
            st0 += ((b0l.x + b0l.y) + (b0l.z + b0l.w)) + ((b0h.x + b0h.y) + (b0h.z + b0h.w));
            st1 += ((b1l.x + b1l.y) + (b1l.z + b1l.w)) + ((b1h.x + b1h.y) + (b1h.z + b1h.w));
        }

        acc00 = __builtin_amdgcn_mfma_f32_16x16x32_bf16(fa0, fb0, acc00, 0, 0, 0);
        acc01 = __builtin_amdgcn_mfma_f32_16x16x32_bf16(fa0, fb1, acc01, 0, 0, 0);

        if (wlt3) {
            float4 a1l = *(const float4*)(pA1 + o), a1h = *(const float4*)(pA1 + o + 4);
            float t0 = sigmoid_fast(a1l.x), t1 = sigmoid_fast(a1l.y);
            float t2 = sigmoid_fast(a1l.z), t3 = sigmoid_fast(a1l.w);
            float t4 = sigmoid_fast(a1h.x), t5 = sigmoid_fast(a1h.y);
            float t6 = sigmoid_fast(a1h.z), t7 = sigmoid_fast(a1h.w);
            spB += ((t0 + t1) + (t2 + t3)) + ((t4 + t5) + (t6 + t7));
            bf16x8 fa1 = pack8(t0, t1, t2, t3, t4, t5, t6, t7);
            acc10 = __builtin_amdgcn_mfma_f32_16x16x32_bf16(fa1, fb0, acc10, 0, 0, 0);
            acc11 = __builtin_amdgcn_mfma_f32_16x16x32_bf16(fa1, fb1, acc11, 0, 0, 0);
        }
    }

    // reduce row-sums across the 4 kg lane-groups (lanes lr, 16+lr, 32+lr, 48+lr)
    spA += __shfl_xor(spA, 16, 64); spA += __shfl_xor(spA, 32, 64);
    spB += __shfl_xor(spB, 16, 64); spB += __shfl_xor(spB, 32, 64);
    st0 += __shfl_xor(st0, 16, 64); st0 += __shfl_xor(st0, 32, 64);
    st1 += __shfl_xor(st1, 16, 64); st1 += __shfl_xor(st1, 32, 64);

    float* wsb = ws + (size_t)(b * KBW + slot) * Pp;
    if (lane < 16) {  // kg==0, lr==lane
        if (vA0)  wsb[SP_OFF + rA0] = spA;
        if (wlt3) wsb[SP_OFF + rA1] = spB;
        if (w == 0) {
            wsb[ST_OFF + lr] = st0;
            if (lr < 4) wsb[ST_OFF + 16 + lr] = st1;
        }
    }

    // dot partials: C/D layout col=lane&15 (m), row=kg*4+e (n-local); each
    // acc fx4 covers 4 consecutive n -> float4 stores.
    const int nb = 32 * w + kg * 4;
    if (nb < Nn) {
        *(float4*)&wsb[lr * NP + nb] = *(float4*)&acc00;
        if (lr < 4) *(float4*)&wsb[(16 + lr) * NP + nb] = *(float4*)&acc01;
    }
    if (wlt3) {
        *(float4*)&wsb[lr * NP + nb + 16] = *(float4*)&acc10;
        if (lr < 4) *(float4*)&wsb[(16 + lr) * NP + nb + 16] = *(float4*)&acc11;
    }
}

// Stage 1: reduce 512 slots -> 16 groups of 32, coalesced, 256 blocks.
__global__ __launch_bounds__(256) void hung_red(
    const float* __restrict__ ws, float* __restrict__ ws2)
{
    const int g  = blockIdx.x;   // 0..GRP-1
    const int b  = blockIdx.y;   // 0..Bb-1
    const int jc = blockIdx.z;   // 0..JC-1
    const float* base = ws + ((size_t)b * KBW + (size_t)g * SPG) * Pp;
    float* outb = ws2 + ((size_t)b * GRP + g) * Pp;
    for (int j = jc * 256 + threadIdx.x; j < Pp; j += 256 * JC) {
        float s = 0.f;
        #pragma unroll 8
        for (int k = 0; k < SPG; ++k) s += base[(size_t)k * Pp + j];
        outb[j] = s;
    }
}

__global__ __launch_bounds__(256) void hung_fin(
    const float* __restrict__ ws2,
    const float* __restrict__ logits,   // (B,N,C)
    const int*   __restrict__ labels,   // (B,M)
    float* __restrict__ out)            // (B,N,M)
{
    int t = blockIdx.x * 256 + threadIdx.x;
    if (t >= Bb * Nn * Mm) return;
    int b = t / (Nn * Mm);
    int r = t % (Nn * Mm);
    int m = r / Nn;       // n fast-varying -> coalesced ws2 reads
    int n = r % Nn;

    const float* p = ws2 + (size_t)b * GRP * Pp;
    float dot = 0.f, sp = 0.f, st = 0.f;
    #pragma unroll
    for (int g = 0; g < GRP; ++g) {
        dot += p[m * NP + n];
        sp  += p[SP_OFF + n];
        st  += p[ST_OFF + m];
        p += Pp;
    }

    int lab = labels[b * Mm + m];
    float cc = -logits[(size_t)(b * Nn + n) * Cc + lab];
    const float invL = 1.0f / (float)Lsz;
    float cm = -(2.f * dot + (float)Lsz - sp - st) * invL;
    float cd = 1.f - (2.f * dot + 1.f) / (sp + st + 1.f);
    out[(size_t)b * (Nn * Mm) + n * Mm + m] = cc + cm + cd;
}

extern "C" void kernel_launch(void* const* d_in, const int* in_sizes, int n_in,
                              void* d_out, int out_size, void* d_ws, size_t ws_size,
                              hipStream_t stream) {
    const float* logits = (const float*)d_in[0];
    const float* pmasks = (const float*)d_in[1];
    const int*   labels = (const int*)d_in[2];
    const float* gmasks = (const float*)d_in[3];
    float* out = (float*)d_out;
    float* ws  = (float*)d_ws;                         // Bb*KBW*Pp = 19.5 MB
    float* ws2 = ws + (size_t)Bb * KBW * Pp;           // Bb*GRP*Pp = 610 KB

    hung_main<<<dim3(KBW, Bb), 256, 0, stream>>>(pmasks, gmasks, ws);
    hung_red<<<dim3(GRP, Bb, JC), 256, 0, stream>>>(ws, ws2);
    hung_fin<<<(Bb * Nn * Mm + 255) / 256, 256, 0, stream>>>(ws2, logits, labels, out);
}